// Round 2
// baseline (1337.714 us; speedup 1.0000x reference)
//
#include <hip/hip_runtime.h>
#include <hip/hip_bf16.h>
#include <stdint.h>

// Problem: B=64, T=128, F=16, H=512, S=2.  All inputs fp32, lengths int32, out fp32 [64][14].
//
// Pipeline:
//  prep1: fold W_is into W_ih (Wc0/Wc1, K=8/6), fold biases (bc), cast W_hh / W_ih[:,512:1536] to bf16
//  prep2: h_hist[0] = h0 (bf16, both segments), zero flags  (flags are in poisoned ws -> must re-init every launch)
//  tembk: t_emb[8192][1024] bf16  (cos/sin embedding of x[:,:,0:2])
//  gemmB: G_temb[8192][2048] = t_emb @ W_ih[:,512:1536].T   (bf16 MFMA, fp32 acc, bf16 store)
//  lstmk: persistent 128-block recurrence, W_hh B-fragments resident in VGPRs,
//         cross-block h exchange via agent-scope atomics + per-(step,rowgroup) flag lines
//  outk : out = sigmoid(hfin @ W_o.T + b_o)
//
// Reshape quirk (faithful to torch): concat(dim=1).reshape(B,S,T,3H) interleaves:
//   segment s', step t' uses source timestep n_t=(s'*128+t')>>1 and embedding branch n_s=(s'*128+t')&1.
//
// R1 fix: h staging in lstmk loaded only 16 of each thread's 32 bf16 columns ->
// half of h_l was uninitialized LDS -> inf-inf -> NaN in MFMA acc. Now hv[8] (64 B/thread).

typedef __attribute__((ext_vector_type(8))) short bf16x8_t;
typedef __attribute__((ext_vector_type(4))) float f32x4_t;

// ---------------- workspace layout (bytes) ----------------
#define OFF_G      0u                      // bf16 [8192][2048]   33,554,432
#define OFF_TEMB   33554432u               // bf16 [8192][1024]   16,777,216
#define OFF_HH     50331648u               // bf16 [129][128][512] 16,908,288
#define OFF_WHH    67239936u               // bf16 [2048][512]     2,097,152
#define OFF_WMID   69337088u               // bf16 [2048][1024]    4,194,304
#define OFF_WC0    73531392u               // f32  [2048][8]          65,536
#define OFF_WC1    73596928u               // f32  [2048][8] (6 used) 65,536
#define OFF_BC     73662464u               // f32  [2][2048]          16,384
#define OFF_HFIN   73678848u               // f32  [64][1024]        262,144
#define OFF_FLAGS  73940992u               // u32  [129][8][16]       66,048
// total ~74 MB

__device__ __forceinline__ float bf2f(uint16_t u){
  union { uint32_t i; float f; } v; v.i = ((uint32_t)u) << 16; return v.f;
}
__device__ __forceinline__ uint16_t f2b(float f){
  union { float f; uint32_t i; } v; v.f = f;
  uint32_t r = v.i + 0x7fffu + ((v.i >> 16) & 1u);  // RNE
  return (uint16_t)(r >> 16);
}
__device__ __forceinline__ float sigm(float x){ return 1.0f/(1.0f + __expf(-x)); }
__device__ __forceinline__ float tanh_(float x){
  float xc = fminf(fmaxf(x, -15.f), 15.f);
  float t = __expf(2.f*xc);
  return (t - 1.f)/(t + 1.f);
}

// ---------------- prep1: weight folding + bf16 casts ----------------
__global__ void prep1(const float* __restrict__ W_ih, const float* __restrict__ W_hh,
                      const float* __restrict__ W_is0, const float* __restrict__ b_is0,
                      const float* __restrict__ W_is1, const float* __restrict__ b_is1,
                      const float* __restrict__ b_ih, const float* __restrict__ b_hh,
                      uint16_t* __restrict__ whh_b, uint16_t* __restrict__ wmid_b,
                      float* __restrict__ wc0, float* __restrict__ wc1, float* __restrict__ bc){
  const int n = blockIdx.x;        // gate column 0..2047
  const int tid = threadIdx.x;     // 256
  __shared__ float wrow[512];
  wrow[tid]       = W_ih[(size_t)n*1536 + tid];
  wrow[tid + 256] = W_ih[(size_t)n*1536 + 256 + tid];
  for (int j = tid; j < 1024; j += 256)
    wmid_b[(size_t)n*1024 + j] = f2b(W_ih[(size_t)n*1536 + 512 + j]);
  for (int k = tid; k < 512; k += 256)
    whh_b[(size_t)n*512 + k] = f2b(W_hh[(size_t)n*512 + k]);
  __syncthreads();
  if (tid < 8){
    float s = 0.f;
    for (int k = 0; k < 512; ++k) s += wrow[k]*W_is0[k*8 + tid];
    wc0[n*8 + tid] = s;
  } else if (tid < 16){
    int c = tid - 8;
    float s = 0.f;
    if (c < 6){ for (int k = 0; k < 512; ++k) s += wrow[k]*W_is1[k*6 + c]; }
    wc1[n*8 + c] = s;              // c==6,7 stay 0 (stride-8 padding)
  } else if (tid == 16){
    float s = b_ih[n] + b_hh[n];
    for (int k = 0; k < 512; ++k) s += wrow[k]*b_is0[k];
    bc[n] = s;
  } else if (tid == 17){
    float s = b_ih[n] + b_hh[n];
    for (int k = 0; k < 512; ++k) s += wrow[k]*b_is1[k];
    bc[2048 + n] = s;
  }
}

// ---------------- prep2: h_hist[0] + flag re-init (ws is poisoned each launch!) ----------------
__global__ void prep2(const float* __restrict__ h0, uint16_t* __restrict__ h_hist,
                      uint32_t* __restrict__ flags){
  int i = blockIdx.x*256 + threadIdx.x;   // grid 256 -> 65536 threads
  if (i < 65536){
    int rw = i >> 9, k = i & 511;         // row = (s*64+b), both segments start at h0[b]
    h_hist[i] = f2b(h0[(size_t)(rw & 63)*512 + k]);
  }
  if (i < 129*8*16) flags[i] = 0u;
}

// ---------------- tembk: timestep embedding, bf16 ----------------
__global__ void tembk(const float* __restrict__ x, uint16_t* __restrict__ temb){
  const int rid = blockIdx.x;       // (b*128 + t)
  const int k = threadIdx.x;        // 0..255
  float x0 = x[(size_t)rid*16 + 0], x1 = x[(size_t)rid*16 + 1];
  float f = __expf((float)k * (-9.210340371976184f/256.f));  // 10000^(-k/256)
  float a0 = x0*f, a1 = x1*f;
  size_t base = (size_t)rid*1024;
  temb[base + k]        = f2b(__cosf(a0));
  temb[base + 256 + k]  = f2b(__sinf(a0));
  temb[base + 512 + k]  = f2b(__cosf(a1));
  temb[base + 768 + k]  = f2b(__sinf(a1));
}

// ---------------- gemmB: G = temb[8192,1024] @ wmid[2048,1024]^T  (bf16 MFMA) ----------------
__launch_bounds__(256)
__global__ void gemmB(const uint16_t* __restrict__ temb, const uint16_t* __restrict__ wmid,
                      uint16_t* __restrict__ G){
  __shared__ __align__(16) uint16_t Al[128][72];  // 64 + 8 pad
  __shared__ __align__(16) uint16_t Bl[128][72];
  const int tid = threadIdx.x;
  const int m0 = blockIdx.x*128, n0 = blockIdx.y*128;
  const int w = tid >> 6, lane = tid & 63;
  const int q = lane >> 4, ln = lane & 15;
  const int wm = w >> 1, wn = w & 1;
  const int srow = tid >> 1, shalf = tid & 1;

  f32x4_t acc[4][4];
  #pragma unroll
  for (int a = 0; a < 4; ++a)
    #pragma unroll
    for (int b = 0; b < 4; ++b) acc[a][b] = (f32x4_t){0.f,0.f,0.f,0.f};

  for (int kb = 0; kb < 16; ++kb){
    const uint4* ga = (const uint4*)(temb + (size_t)(m0 + srow)*1024 + kb*64 + shalf*32);
    const uint4* gb = (const uint4*)(wmid + (size_t)(n0 + srow)*1024 + kb*64 + shalf*32);
    uint4 va[4], vb[4];
    #pragma unroll
    for (int i = 0; i < 4; ++i){ va[i] = ga[i]; vb[i] = gb[i]; }
    #pragma unroll
    for (int i = 0; i < 4; ++i){
      *(uint4*)&Al[srow][shalf*32 + i*8] = va[i];
      *(uint4*)&Bl[srow][shalf*32 + i*8] = vb[i];
    }
    __syncthreads();
    #pragma unroll
    for (int kc = 0; kc < 2; ++kc){
      bf16x8_t af[4], bf[4];
      #pragma unroll
      for (int mt = 0; mt < 4; ++mt) af[mt] = *(const bf16x8_t*)&Al[wm*64 + mt*16 + ln][kc*32 + q*8];
      #pragma unroll
      for (int nt = 0; nt < 4; ++nt) bf[nt] = *(const bf16x8_t*)&Bl[wn*64 + nt*16 + ln][kc*32 + q*8];
      #pragma unroll
      for (int mt = 0; mt < 4; ++mt)
        #pragma unroll
        for (int nt = 0; nt < 4; ++nt)
          acc[mt][nt] = __builtin_amdgcn_mfma_f32_16x16x32_bf16(af[mt], bf[nt], acc[mt][nt], 0, 0, 0);
    }
    __syncthreads();
  }
  #pragma unroll
  for (int mt = 0; mt < 4; ++mt)
    #pragma unroll
    for (int nt = 0; nt < 4; ++nt)
      #pragma unroll
      for (int r = 0; r < 4; ++r){
        int Mr = m0 + wm*64 + mt*16 + q*4 + r;    // C/D: col=lane&15, row=quad*4+reg (m89-verified)
        int Nc = n0 + wn*64 + nt*16 + ln;
        G[(size_t)Mr*2048 + Nc] = f2b(acc[mt][nt][r]);
      }
}

// ---------------- lstmk: persistent recurrence ----------------
// 128 blocks = 8 row-groups (16 rows of (s,b)) x 16 col-groups (32 hidden units -> 128 gate cols).
// blockIdx = g*8 + r so all 16 col-groups of a row-group share an XCD (perf heuristic only;
// correctness uses agent-scope atomics throughout).
__launch_bounds__(256)
__global__ void lstmk(const float* __restrict__ x, const float* __restrict__ c0,
                      const int* __restrict__ lengths,
                      const uint16_t* __restrict__ whh_b, const uint16_t* __restrict__ G,
                      const float* __restrict__ wc0, const float* __restrict__ wc1,
                      const float* __restrict__ bc,
                      uint16_t* __restrict__ h_hist, float* __restrict__ hfin,
                      uint32_t* __restrict__ flags){
  __shared__ __align__(16) uint16_t h_l[16][520];   // 16 rows x 512 K, +8 pad (bank spread)
  __shared__ float gbuf[16][128];                   // staged G_temb slice (fp32)
  __shared__ float gates_l[4][16][32];              // i,f,g,o  x row x unit
  __shared__ float wc_l[2][128][8];
  __shared__ float bc_l[2][128];
  __shared__ float xf_l[16][8];

  const int tid = threadIdx.x;
  const int bid = blockIdx.x;
  const int rr = bid & 7;         // row-group
  const int g  = bid >> 3;        // col-group
  const int k0 = g*32;
  const int sp = rr >> 2;         // segment of this row-group
  const int w = tid >> 6, lane = tid & 63;
  const int q = lane >> 4, ln = lane & 15;

  // W_hh B-fragments resident in VGPRs: wave w = gate type w; 2 N-tiles x 16 K-chunks.
  bf16x8_t barr[2][16];
  #pragma unroll
  for (int tt = 0; tt < 2; ++tt){
    int n = w*512 + k0 + tt*16 + ln;
    #pragma unroll
    for (int kc = 0; kc < 16; ++kc)
      barr[tt][kc] = *(const bf16x8_t*)(whh_b + (size_t)n*512 + kc*32 + q*8);
  }

  for (int i = tid; i < 2048; i += 256){
    int nsI = i >> 10, l = (i >> 3) & 127, c = i & 7;
    int n = (l >> 5)*512 + k0 + (l & 31);
    wc_l[nsI][l][c] = nsI ? wc1[n*8 + c] : wc0[n*8 + c];
  }
  if (tid < 256){
    int nsI = tid >> 7, l = tid & 127;
    int n = (l >> 5)*512 + k0 + (l & 31);
    bc_l[nsI][l] = bc[nsI*2048 + n];
  }

  // cell-state ownership: thread -> (row um, units u2,u2+1)
  const int um = tid >> 4;
  const int u2 = (tid & 15)*2;
  const int rowm = rr*16 + um;
  const int bm_u = rowm & 63;
  float cst0 = c0[(size_t)bm_u*512 + k0 + u2];
  float cst1 = c0[(size_t)bm_u*512 + k0 + u2 + 1];
  const int lenm = lengths[bm_u];

  // G staging map: thread -> (row gm, 8-col chunk cp)
  const int gm = tid >> 4, cp = tid & 15;
  const int l0 = cp*8;
  const int gcol = (l0 >> 5)*512 + k0 + (l0 & 31);
  const int gb_ = (rr*16 + gm) & 63;
  // xf staging map (tid<128): (row xm, col xc)
  const int xm = tid >> 3, xc = tid & 7;
  const int xb = (rr*16 + xm) & 63;

  __syncthreads();

  for (int t = 0; t < 128; ++t){
    const int qidx = sp*128 + t;
    const int ntm = qidx >> 1;     // source timestep (reshape interleave)
    const int ns  = qidx & 1;      // embedding branch

    // --- phase 0: recurrence-independent loads, then stage to LDS (safe: last barrier was sync B) ---
    uint4 gv = *(const uint4*)(G + ((size_t)(gb_*128 + ntm))*2048 + gcol);
    {
      uint32_t uu[4] = {gv.x, gv.y, gv.z, gv.w};
      #pragma unroll
      for (int i = 0; i < 4; ++i){
        gbuf[gm][l0 + i*2]     = bf2f((uint16_t)(uu[i] & 0xffffu));
        gbuf[gm][l0 + i*2 + 1] = bf2f((uint16_t)(uu[i] >> 16));
      }
    }
    if (tid < 128){
      float xv = 0.f;
      if (ns == 0)      xv = x[(size_t)(xb*128 + ntm)*16 + 2 + xc];
      else if (xc < 6)  xv = x[(size_t)(xb*128 + ntm)*16 + 10 + xc];
      xf_l[xm][xc] = xv;
    }

    // --- phase 1: wait for h_t from the 16 producers of this row-group ---
    if (t > 0){
      uint32_t* fl = (uint32_t*)(flags + ((size_t)t*8 + rr)*16);
      while (true){
        uint32_t v = __hip_atomic_load(&fl[ln], __ATOMIC_ACQUIRE, __HIP_MEMORY_SCOPE_AGENT);
        if (__all(v != 0u)) break;
        __builtin_amdgcn_s_sleep(1);
      }
    }
    // stage h_t: each thread covers 32 bf16 (512 cols / 16 threads-per-row) = 8x 8B agent loads
    {
      const int hm = tid >> 4, sg = tid & 15;
      unsigned long long* hp = (unsigned long long*)
          (h_hist + ((size_t)t*128 + rr*16 + hm)*512 + sg*32);
      unsigned long long hv[8];
      #pragma unroll
      for (int i = 0; i < 8; ++i)
        hv[i] = __hip_atomic_load(&hp[i], __ATOMIC_RELAXED, __HIP_MEMORY_SCOPE_AGENT);
      #pragma unroll
      for (int i = 0; i < 8; ++i)
        *(unsigned long long*)&h_l[hm][sg*32 + i*4] = hv[i];
    }
    __syncthreads();   // sync 1

    // --- phase 2: gates_hh = h @ Whh_slice^T ---
    f32x4_t acc0 = (f32x4_t){0,0,0,0}, acc1 = (f32x4_t){0,0,0,0};
    #pragma unroll
    for (int kc = 0; kc < 16; ++kc){
      bf16x8_t a = *(const bf16x8_t*)&h_l[ln][kc*32 + q*8];  // A[m=lane&15][k=quad*8+j]
      acc0 = __builtin_amdgcn_mfma_f32_16x16x32_bf16(a, barr[0][kc], acc0, 0, 0, 0);
      acc1 = __builtin_amdgcn_mfma_f32_16x16x32_bf16(a, barr[1][kc], acc1, 0, 0, 0);
    }

    // --- phase 3: + input gates (G_temb + folded xf part + biases) -> gates_l ---
    #pragma unroll
    for (int tt = 0; tt < 2; ++tt){
      f32x4_t av = tt ? acc1 : acc0;
      int u = tt*16 + ln;
      int l = w*32 + u;
      #pragma unroll
      for (int r = 0; r < 4; ++r){
        int m = q*4 + r;
        float val = av[r] + gbuf[m][l] + bc_l[ns][l];
        #pragma unroll
        for (int c = 0; c < 8; ++c) val += wc_l[ns][l][c]*xf_l[m][c];
        gates_l[w][m][u] = val;
      }
    }
    __syncthreads();   // sync A

    // --- phase 4: cell update (torch order i,f,g,o) ---
    {
      float ig0 = gates_l[0][um][u2], ig1 = gates_l[0][um][u2+1];
      float fg0 = gates_l[1][um][u2], fg1 = gates_l[1][um][u2+1];
      float gg0 = gates_l[2][um][u2], gg1 = gates_l[2][um][u2+1];
      float og0 = gates_l[3][um][u2], og1 = gates_l[3][um][u2+1];
      cst0 = sigm(fg0)*cst0 + sigm(ig0)*tanh_(gg0);
      cst1 = sigm(fg1)*cst1 + sigm(ig1)*tanh_(gg1);
      float h0v = sigm(og0)*tanh_(cst0);
      float h1v = sigm(og1)*tanh_(cst1);
      uint32_t packed = (uint32_t)f2b(h0v) | ((uint32_t)f2b(h1v) << 16);
      uint32_t* hp = (uint32_t*)(h_hist + ((size_t)(t+1)*128 + rowm)*512 + k0 + u2);
      // write-through to LLC so consumers on other XCDs see it
      __hip_atomic_store(hp, packed, __ATOMIC_RELAXED, __HIP_MEMORY_SCOPE_AGENT);
      if (t == lenm - 1){
        hfin[(size_t)bm_u*1024 + sp*512 + k0 + u2]     = h0v;
        hfin[(size_t)bm_u*1024 + sp*512 + k0 + u2 + 1] = h1v;
      }
    }
    __syncthreads();   // sync B: all threads' agent stores drained (vmcnt(0)) before flag
    if (tid == 0)
      __hip_atomic_store((uint32_t*)&flags[((size_t)(t+1)*8 + rr)*16 + g], 1u,
                         __ATOMIC_RELEASE, __HIP_MEMORY_SCOPE_AGENT);
  }
}

// ---------------- outk: out = sigmoid(hfin @ W_o^T + b_o) ----------------
__global__ void outk(const float* __restrict__ hfin, const float* __restrict__ W_o,
                     const float* __restrict__ b_o, float* __restrict__ out){
  __shared__ float hl[1024];
  __shared__ float red[16][17];
  const int b = blockIdx.x, tid = threadIdx.x;
  #pragma unroll
  for (int i = 0; i < 4; ++i) hl[tid + i*256] = hfin[(size_t)b*1024 + tid + i*256];
  __syncthreads();
  const int o = tid >> 4, j0 = tid & 15;
  float s = 0.f;
  if (o < 14){
    for (int j = j0; j < 1024; j += 16) s += hl[j]*W_o[(size_t)o*1024 + j];
  }
  red[o][j0] = s;
  __syncthreads();
  if (tid < 14){
    float tot = b_o[tid];
    #pragma unroll
    for (int i = 0; i < 16; ++i) tot += red[tid][i];
    out[b*14 + tid] = 1.0f/(1.0f + __expf(-tot));
  }
}

extern "C" void kernel_launch(void* const* d_in, const int* in_sizes, int n_in,
                              void* d_out, int out_size, void* d_ws, size_t ws_size,
                              hipStream_t stream){
  const float* x     = (const float*)d_in[0];
  const int*   lens  = (const int*)  d_in[1];
  const float* h0    = (const float*)d_in[2];
  const float* c0    = (const float*)d_in[3];
  const float* W_is0 = (const float*)d_in[4];
  const float* b_is0 = (const float*)d_in[5];
  const float* W_is1 = (const float*)d_in[6];
  const float* b_is1 = (const float*)d_in[7];
  const float* W_ih  = (const float*)d_in[8];
  const float* W_hh  = (const float*)d_in[9];
  const float* b_ih  = (const float*)d_in[10];
  const float* b_hh  = (const float*)d_in[11];
  const float* W_o   = (const float*)d_in[12];
  const float* b_o   = (const float*)d_in[13];
  float* out = (float*)d_out;

  char* ws = (char*)d_ws;   // needs ~74 MB
  uint16_t* G      = (uint16_t*)(ws + OFF_G);
  uint16_t* temb   = (uint16_t*)(ws + OFF_TEMB);
  uint16_t* h_hist = (uint16_t*)(ws + OFF_HH);
  uint16_t* whh_b  = (uint16_t*)(ws + OFF_WHH);
  uint16_t* wmid_b = (uint16_t*)(ws + OFF_WMID);
  float* wc0  = (float*)(ws + OFF_WC0);
  float* wc1  = (float*)(ws + OFF_WC1);
  float* bc   = (float*)(ws + OFF_BC);
  float* hfin = (float*)(ws + OFF_HFIN);
  uint32_t* flags = (uint32_t*)(ws + OFF_FLAGS);

  hipLaunchKernelGGL(prep1, dim3(2048), dim3(256), 0, stream,
                     W_ih, W_hh, W_is0, b_is0, W_is1, b_is1, b_ih, b_hh,
                     whh_b, wmid_b, wc0, wc1, bc);
  hipLaunchKernelGGL(prep2, dim3(256), dim3(256), 0, stream, h0, h_hist, flags);
  hipLaunchKernelGGL(tembk, dim3(8192), dim3(256), 0, stream, x, temb);
  hipLaunchKernelGGL(gemmB, dim3(64, 16), dim3(256), 0, stream, temb, wmid_b, G);
  hipLaunchKernelGGL(lstmk, dim3(128), dim3(256), 0, stream,
                     x, c0, lens, whh_b, G, wc0, wc1, bc, h_hist, hfin, flags);
  hipLaunchKernelGGL(outk, dim3(64), dim3(256), 0, stream, hfin, W_o, b_o, out);
}

// Round 3
// 831.387 us; speedup vs baseline: 1.6090x; 1.6090x over previous
//
#include <hip/hip_runtime.h>
#include <hip/hip_bf16.h>
#include <stdint.h>

// Problem: B=64, T=128, F=16, H=512, S=2.  All inputs fp32, lengths int32, out fp32 [64][14].
//
// Pipeline:
//  prep1: fold W_is into W_ih (Wc0/Wc1, K=8/6), fold biases (bc), cast W_hh / W_ih[:,512:1536] to bf16
//  prep2: h_hist[0] = h0 (bf16, both segments), zero flags  (flags are in poisoned ws -> must re-init every launch)
//  tembk: t_emb[8192][1024] bf16  (cos/sin embedding of x[:,:,0:2])
//  gemmB: G_temb[8192][2048] = t_emb @ W_ih[:,512:1536].T   (bf16 MFMA, fp32 acc, bf16 store)
//  lstmk: persistent 128-block recurrence, W_hh B-fragments resident in VGPRs,
//         cross-block h exchange via agent-scope (LLC) loads/stores + per-(step,rowgroup) flag lines
//  outk : out = sigmoid(hfin @ W_o.T + b_o)
//
// Reshape quirk (faithful to torch): concat(dim=1).reshape(B,S,T,3H) interleaves:
//   segment s', step t' uses source timestep n_t=(s'*128+t')>>1 and embedding branch n_s=(s'*128+t')&1.
//
// R1 fix: h staging loaded only 16 of 32 bf16 cols/thread -> NaN from uninit LDS. Now 8x8B.
// R2 fix: poll loop used ACQUIRE agent loads -> buffer_inv (L1/L2 invalidate) EVERY iteration
//   across 512 spinning waves -> 8.9us/step of cache-inv congestion (MfmaUtil 1.2%).
//   Poll is now RELAXED; correctness: producer drains h-stores to LLC (vmcnt0 at sync B)
//   before the RELEASE flag store, and consumer h-loads are themselves agent-scope
//   (cache-bypassing) issued only after the poll exits -> they read final LLC data.
//   A workgroup-scope acquire fence after the poll is kept as a compiler barrier only.

typedef __attribute__((ext_vector_type(8))) short bf16x8_t;
typedef __attribute__((ext_vector_type(4))) float f32x4_t;

// ---------------- workspace layout (bytes) ----------------
#define OFF_G      0u                      // bf16 [8192][2048]   33,554,432
#define OFF_TEMB   33554432u               // bf16 [8192][1024]   16,777,216
#define OFF_HH     50331648u               // bf16 [129][128][512] 16,908,288
#define OFF_WHH    67239936u               // bf16 [2048][512]     2,097,152
#define OFF_WMID   69337088u               // bf16 [2048][1024]    4,194,304
#define OFF_WC0    73531392u               // f32  [2048][8]          65,536
#define OFF_WC1    73596928u               // f32  [2048][8] (6 used) 65,536
#define OFF_BC     73662464u               // f32  [2][2048]          16,384
#define OFF_HFIN   73678848u               // f32  [64][1024]        262,144
#define OFF_FLAGS  73940992u               // u32  [129][8][16]       66,048
// total ~74 MB

__device__ __forceinline__ float bf2f(uint16_t u){
  union { uint32_t i; float f; } v; v.i = ((uint32_t)u) << 16; return v.f;
}
__device__ __forceinline__ uint16_t f2b(float f){
  union { float f; uint32_t i; } v; v.f = f;
  uint32_t r = v.i + 0x7fffu + ((v.i >> 16) & 1u);  // RNE
  return (uint16_t)(r >> 16);
}
__device__ __forceinline__ float sigm(float x){ return 1.0f/(1.0f + __expf(-x)); }
__device__ __forceinline__ float tanh_(float x){
  float xc = fminf(fmaxf(x, -15.f), 15.f);
  float t = __expf(2.f*xc);
  return (t - 1.f)/(t + 1.f);
}

// ---------------- prep1: weight folding + bf16 casts ----------------
__global__ void prep1(const float* __restrict__ W_ih, const float* __restrict__ W_hh,
                      const float* __restrict__ W_is0, const float* __restrict__ b_is0,
                      const float* __restrict__ W_is1, const float* __restrict__ b_is1,
                      const float* __restrict__ b_ih, const float* __restrict__ b_hh,
                      uint16_t* __restrict__ whh_b, uint16_t* __restrict__ wmid_b,
                      float* __restrict__ wc0, float* __restrict__ wc1, float* __restrict__ bc){
  const int n = blockIdx.x;        // gate column 0..2047
  const int tid = threadIdx.x;     // 256
  __shared__ float wrow[512];
  wrow[tid]       = W_ih[(size_t)n*1536 + tid];
  wrow[tid + 256] = W_ih[(size_t)n*1536 + 256 + tid];
  for (int j = tid; j < 1024; j += 256)
    wmid_b[(size_t)n*1024 + j] = f2b(W_ih[(size_t)n*1536 + 512 + j]);
  for (int k = tid; k < 512; k += 256)
    whh_b[(size_t)n*512 + k] = f2b(W_hh[(size_t)n*512 + k]);
  __syncthreads();
  if (tid < 8){
    float s = 0.f;
    for (int k = 0; k < 512; ++k) s += wrow[k]*W_is0[k*8 + tid];
    wc0[n*8 + tid] = s;
  } else if (tid < 16){
    int c = tid - 8;
    float s = 0.f;
    if (c < 6){ for (int k = 0; k < 512; ++k) s += wrow[k]*W_is1[k*6 + c]; }
    wc1[n*8 + c] = s;              // c==6,7 stay 0 (stride-8 padding)
  } else if (tid == 16){
    float s = b_ih[n] + b_hh[n];
    for (int k = 0; k < 512; ++k) s += wrow[k]*b_is0[k];
    bc[n] = s;
  } else if (tid == 17){
    float s = b_ih[n] + b_hh[n];
    for (int k = 0; k < 512; ++k) s += wrow[k]*b_is1[k];
    bc[2048 + n] = s;
  }
}

// ---------------- prep2: h_hist[0] + flag re-init (ws is poisoned each launch!) ----------------
__global__ void prep2(const float* __restrict__ h0, uint16_t* __restrict__ h_hist,
                      uint32_t* __restrict__ flags){
  int i = blockIdx.x*256 + threadIdx.x;   // grid 256 -> 65536 threads
  if (i < 65536){
    int rw = i >> 9, k = i & 511;         // row = (s*64+b), both segments start at h0[b]
    h_hist[i] = f2b(h0[(size_t)(rw & 63)*512 + k]);
  }
  if (i < 129*8*16) flags[i] = 0u;
}

// ---------------- tembk: timestep embedding, bf16 ----------------
__global__ void tembk(const float* __restrict__ x, uint16_t* __restrict__ temb){
  const int rid = blockIdx.x;       // (b*128 + t)
  const int k = threadIdx.x;        // 0..255
  float x0 = x[(size_t)rid*16 + 0], x1 = x[(size_t)rid*16 + 1];
  float f = __expf((float)k * (-9.210340371976184f/256.f));  // 10000^(-k/256)
  float a0 = x0*f, a1 = x1*f;
  size_t base = (size_t)rid*1024;
  temb[base + k]        = f2b(__cosf(a0));
  temb[base + 256 + k]  = f2b(__sinf(a0));
  temb[base + 512 + k]  = f2b(__cosf(a1));
  temb[base + 768 + k]  = f2b(__sinf(a1));
}

// ---------------- gemmB: G = temb[8192,1024] @ wmid[2048,1024]^T  (bf16 MFMA) ----------------
__launch_bounds__(256)
__global__ void gemmB(const uint16_t* __restrict__ temb, const uint16_t* __restrict__ wmid,
                      uint16_t* __restrict__ G){
  __shared__ __align__(16) uint16_t Al[128][72];  // 64 + 8 pad
  __shared__ __align__(16) uint16_t Bl[128][72];
  const int tid = threadIdx.x;
  const int m0 = blockIdx.x*128, n0 = blockIdx.y*128;
  const int w = tid >> 6, lane = tid & 63;
  const int q = lane >> 4, ln = lane & 15;
  const int wm = w >> 1, wn = w & 1;
  const int srow = tid >> 1, shalf = tid & 1;

  f32x4_t acc[4][4];
  #pragma unroll
  for (int a = 0; a < 4; ++a)
    #pragma unroll
    for (int b = 0; b < 4; ++b) acc[a][b] = (f32x4_t){0.f,0.f,0.f,0.f};

  for (int kb = 0; kb < 16; ++kb){
    const uint4* ga = (const uint4*)(temb + (size_t)(m0 + srow)*1024 + kb*64 + shalf*32);
    const uint4* gb = (const uint4*)(wmid + (size_t)(n0 + srow)*1024 + kb*64 + shalf*32);
    uint4 va[4], vb[4];
    #pragma unroll
    for (int i = 0; i < 4; ++i){ va[i] = ga[i]; vb[i] = gb[i]; }
    #pragma unroll
    for (int i = 0; i < 4; ++i){
      *(uint4*)&Al[srow][shalf*32 + i*8] = va[i];
      *(uint4*)&Bl[srow][shalf*32 + i*8] = vb[i];
    }
    __syncthreads();
    #pragma unroll
    for (int kc = 0; kc < 2; ++kc){
      bf16x8_t af[4], bf[4];
      #pragma unroll
      for (int mt = 0; mt < 4; ++mt) af[mt] = *(const bf16x8_t*)&Al[wm*64 + mt*16 + ln][kc*32 + q*8];
      #pragma unroll
      for (int nt = 0; nt < 4; ++nt) bf[nt] = *(const bf16x8_t*)&Bl[wn*64 + nt*16 + ln][kc*32 + q*8];
      #pragma unroll
      for (int mt = 0; mt < 4; ++mt)
        #pragma unroll
        for (int nt = 0; nt < 4; ++nt)
          acc[mt][nt] = __builtin_amdgcn_mfma_f32_16x16x32_bf16(af[mt], bf[nt], acc[mt][nt], 0, 0, 0);
    }
    __syncthreads();
  }
  #pragma unroll
  for (int mt = 0; mt < 4; ++mt)
    #pragma unroll
    for (int nt = 0; nt < 4; ++nt)
      #pragma unroll
      for (int r = 0; r < 4; ++r){
        int Mr = m0 + wm*64 + mt*16 + q*4 + r;    // C/D: col=lane&15, row=quad*4+reg (m89-verified)
        int Nc = n0 + wn*64 + nt*16 + ln;
        G[(size_t)Mr*2048 + Nc] = f2b(acc[mt][nt][r]);
      }
}

// ---------------- lstmk: persistent recurrence ----------------
// 128 blocks = 8 row-groups (16 rows of (s,b)) x 16 col-groups (32 hidden units -> 128 gate cols).
// blockIdx = g*8 + r so all 16 col-groups of a row-group share an XCD (perf heuristic only;
// correctness uses agent-scope ops throughout).
__launch_bounds__(256)
__global__ void lstmk(const float* __restrict__ x, const float* __restrict__ c0,
                      const int* __restrict__ lengths,
                      const uint16_t* __restrict__ whh_b, const uint16_t* __restrict__ G,
                      const float* __restrict__ wc0, const float* __restrict__ wc1,
                      const float* __restrict__ bc,
                      uint16_t* __restrict__ h_hist, float* __restrict__ hfin,
                      uint32_t* __restrict__ flags){
  __shared__ __align__(16) uint16_t h_l[16][520];   // 16 rows x 512 K, +8 pad (bank spread)
  __shared__ float gbuf[16][128];                   // staged G_temb slice (fp32)
  __shared__ float gates_l[4][16][32];              // i,f,g,o  x row x unit
  __shared__ float wc_l[2][128][8];
  __shared__ float bc_l[2][128];
  __shared__ float xf_l[16][8];

  const int tid = threadIdx.x;
  const int bid = blockIdx.x;
  const int rr = bid & 7;         // row-group
  const int g  = bid >> 3;        // col-group
  const int k0 = g*32;
  const int sp = rr >> 2;         // segment of this row-group
  const int w = tid >> 6, lane = tid & 63;
  const int q = lane >> 4, ln = lane & 15;

  // W_hh B-fragments resident in VGPRs: wave w = gate type w; 2 N-tiles x 16 K-chunks.
  bf16x8_t barr[2][16];
  #pragma unroll
  for (int tt = 0; tt < 2; ++tt){
    int n = w*512 + k0 + tt*16 + ln;
    #pragma unroll
    for (int kc = 0; kc < 16; ++kc)
      barr[tt][kc] = *(const bf16x8_t*)(whh_b + (size_t)n*512 + kc*32 + q*8);
  }

  for (int i = tid; i < 2048; i += 256){
    int nsI = i >> 10, l = (i >> 3) & 127, c = i & 7;
    int n = (l >> 5)*512 + k0 + (l & 31);
    wc_l[nsI][l][c] = nsI ? wc1[n*8 + c] : wc0[n*8 + c];
  }
  if (tid < 256){
    int nsI = tid >> 7, l = tid & 127;
    int n = (l >> 5)*512 + k0 + (l & 31);
    bc_l[nsI][l] = bc[nsI*2048 + n];
  }

  // cell-state ownership: thread -> (row um, units u2,u2+1)
  const int um = tid >> 4;
  const int u2 = (tid & 15)*2;
  const int rowm = rr*16 + um;
  const int bm_u = rowm & 63;
  float cst0 = c0[(size_t)bm_u*512 + k0 + u2];
  float cst1 = c0[(size_t)bm_u*512 + k0 + u2 + 1];
  const int lenm = lengths[bm_u];

  // G staging map: thread -> (row gm, 8-col chunk cp)
  const int gm = tid >> 4, cp = tid & 15;
  const int l0 = cp*8;
  const int gcol = (l0 >> 5)*512 + k0 + (l0 & 31);
  const int gb_ = (rr*16 + gm) & 63;
  // xf staging map (tid<128): (row xm, col xc)
  const int xm = tid >> 3, xc = tid & 7;
  const int xb = (rr*16 + xm) & 7 ? (rr*16 + xm) & 63 : (rr*16 + xm) & 63;

  __syncthreads();

  for (int t = 0; t < 128; ++t){
    const int qidx = sp*128 + t;
    const int ntm = qidx >> 1;     // source timestep (reshape interleave)
    const int ns  = qidx & 1;      // embedding branch

    // --- phase 0: recurrence-independent loads, then stage to LDS (safe: last barrier was sync B) ---
    uint4 gv = *(const uint4*)(G + ((size_t)(gb_*128 + ntm))*2048 + gcol);
    {
      uint32_t uu[4] = {gv.x, gv.y, gv.z, gv.w};
      #pragma unroll
      for (int i = 0; i < 4; ++i){
        gbuf[gm][l0 + i*2]     = bf2f((uint16_t)(uu[i] & 0xffffu));
        gbuf[gm][l0 + i*2 + 1] = bf2f((uint16_t)(uu[i] >> 16));
      }
    }
    if (tid < 128){
      float xv = 0.f;
      if (ns == 0)      xv = x[(size_t)(xb*128 + ntm)*16 + 2 + xc];
      else if (xc < 6)  xv = x[(size_t)(xb*128 + ntm)*16 + 10 + xc];
      xf_l[xm][xc] = xv;
    }

    // --- phase 1: wait for h_t from the 16 producers of this row-group ---
    // RELAXED poll (no per-iteration cache invalidate!). Safe because producer drains
    // h-stores to LLC (vmcnt0 @ sync B) before its RELEASE flag store, and our h-loads
    // below are agent-scope (cache-bypassing) issued only after the poll exits.
    if (t > 0){
      uint32_t* fl = (uint32_t*)(flags + ((size_t)t*8 + rr)*16);
      while (true){
        uint32_t v = __hip_atomic_load(&fl[ln], __ATOMIC_RELAXED, __HIP_MEMORY_SCOPE_AGENT);
        if (__all(v != 0u)) break;
        __builtin_amdgcn_s_sleep(1);
      }
      __builtin_amdgcn_fence(__ATOMIC_ACQUIRE, "workgroup");  // compiler barrier; no L2 inv
    }
    // stage h_t: each thread covers 32 bf16 (512 cols / 16 threads-per-row) = 8x 8B agent loads
    {
      const int hm = tid >> 4, sg = tid & 15;
      unsigned long long* hp = (unsigned long long*)
          (h_hist + ((size_t)t*128 + rr*16 + hm)*512 + sg*32);
      unsigned long long hv[8];
      #pragma unroll
      for (int i = 0; i < 8; ++i)
        hv[i] = __hip_atomic_load(&hp[i], __ATOMIC_RELAXED, __HIP_MEMORY_SCOPE_AGENT);
      #pragma unroll
      for (int i = 0; i < 8; ++i)
        *(unsigned long long*)&h_l[hm][sg*32 + i*4] = hv[i];
    }
    __syncthreads();   // sync 1

    // --- phase 2: gates_hh = h @ Whh_slice^T ---
    f32x4_t acc0 = (f32x4_t){0,0,0,0}, acc1 = (f32x4_t){0,0,0,0};
    #pragma unroll
    for (int kc = 0; kc < 16; ++kc){
      bf16x8_t a = *(const bf16x8_t*)&h_l[ln][kc*32 + q*8];  // A[m=lane&15][k=quad*8+j]
      acc0 = __builtin_amdgcn_mfma_f32_16x16x32_bf16(a, barr[0][kc], acc0, 0, 0, 0);
      acc1 = __builtin_amdgcn_mfma_f32_16x16x32_bf16(a, barr[1][kc], acc1, 0, 0, 0);
    }

    // --- phase 3: + input gates (G_temb + folded xf part + biases) -> gates_l ---
    #pragma unroll
    for (int tt = 0; tt < 2; ++tt){
      f32x4_t av = tt ? acc1 : acc0;
      int u = tt*16 + ln;
      int l = w*32 + u;
      #pragma unroll
      for (int r = 0; r < 4; ++r){
        int m = q*4 + r;
        float val = av[r] + gbuf[m][l] + bc_l[ns][l];
        #pragma unroll
        for (int c = 0; c < 8; ++c) val += wc_l[ns][l][c]*xf_l[m][c];
        gates_l[w][m][u] = val;
      }
    }
    __syncthreads();   // sync A

    // --- phase 4: cell update (torch order i,f,g,o) ---
    {
      float ig0 = gates_l[0][um][u2], ig1 = gates_l[0][um][u2+1];
      float fg0 = gates_l[1][um][u2], fg1 = gates_l[1][um][u2+1];
      float gg0 = gates_l[2][um][u2], gg1 = gates_l[2][um][u2+1];
      float og0 = gates_l[3][um][u2], og1 = gates_l[3][um][u2+1];
      cst0 = sigm(fg0)*cst0 + sigm(ig0)*tanh_(gg0);
      cst1 = sigm(fg1)*cst1 + sigm(ig1)*tanh_(gg1);
      float h0v = sigm(og0)*tanh_(cst0);
      float h1v = sigm(og1)*tanh_(cst1);
      uint32_t packed = (uint32_t)f2b(h0v) | ((uint32_t)f2b(h1v) << 16);
      uint32_t* hp = (uint32_t*)(h_hist + ((size_t)(t+1)*128 + rowm)*512 + k0 + u2);
      // write-through to LLC so consumers on other XCDs see it
      __hip_atomic_store(hp, packed, __ATOMIC_RELAXED, __HIP_MEMORY_SCOPE_AGENT);
      if (t == lenm - 1){
        hfin[(size_t)bm_u*1024 + sp*512 + k0 + u2]     = h0v;
        hfin[(size_t)bm_u*1024 + sp*512 + k0 + u2 + 1] = h1v;
      }
    }
    __syncthreads();   // sync B: all threads' agent stores drained (vmcnt(0)) before flag
    if (tid == 0)
      __hip_atomic_store((uint32_t*)&flags[((size_t)(t+1)*8 + rr)*16 + g], 1u,
                         __ATOMIC_RELEASE, __HIP_MEMORY_SCOPE_AGENT);
  }
}

// ---------------- outk: out = sigmoid(hfin @ W_o^T + b_o) ----------------
__global__ void outk(const float* __restrict__ hfin, const float* __restrict__ W_o,
                     const float* __restrict__ b_o, float* __restrict__ out){
  __shared__ float hl[1024];
  __shared__ float red[16][17];
  const int b = blockIdx.x, tid = threadIdx.x;
  #pragma unroll
  for (int i = 0; i < 4; ++i) hl[tid + i*256] = hfin[(size_t)b*1024 + tid + i*256];
  __syncthreads();
  const int o = tid >> 4, j0 = tid & 15;
  float s = 0.f;
  if (o < 14){
    for (int j = j0; j < 1024; j += 16) s += hl[j]*W_o[(size_t)o*1024 + j];
  }
  red[o][j0] = s;
  __syncthreads();
  if (tid < 14){
    float tot = b_o[tid];
    #pragma unroll
    for (int i = 0; i < 16; ++i) tot += red[tid][i];
    out[b*14 + tid] = 1.0f/(1.0f + __expf(-tot));
  }
}

extern "C" void kernel_launch(void* const* d_in, const int* in_sizes, int n_in,
                              void* d_out, int out_size, void* d_ws, size_t ws_size,
                              hipStream_t stream){
  const float* x     = (const float*)d_in[0];
  const int*   lens  = (const int*)  d_in[1];
  const float* h0    = (const float*)d_in[2];
  const float* c0    = (const float*)d_in[3];
  const float* W_is0 = (const float*)d_in[4];
  const float* b_is0 = (const float*)d_in[5];
  const float* W_is1 = (const float*)d_in[6];
  const float* b_is1 = (const float*)d_in[7];
  const float* W_ih  = (const float*)d_in[8];
  const float* W_hh  = (const float*)d_in[9];
  const float* b_ih  = (const float*)d_in[10];
  const float* b_hh  = (const float*)d_in[11];
  const float* W_o   = (const float*)d_in[12];
  const float* b_o   = (const float*)d_in[13];
  float* out = (float*)d_out;

  char* ws = (char*)d_ws;   // needs ~74 MB
  uint16_t* G      = (uint16_t*)(ws + OFF_G);
  uint16_t* temb   = (uint16_t*)(ws + OFF_TEMB);
  uint16_t* h_hist = (uint16_t*)(ws + OFF_HH);
  uint16_t* whh_b  = (uint16_t*)(ws + OFF_WHH);
  uint16_t* wmid_b = (uint16_t*)(ws + OFF_WMID);
  float* wc0  = (float*)(ws + OFF_WC0);
  float* wc1  = (float*)(ws + OFF_WC1);
  float* bc   = (float*)(ws + OFF_BC);
  float* hfin = (float*)(ws + OFF_HFIN);
  uint32_t* flags = (uint32_t*)(ws + OFF_FLAGS);

  hipLaunchKernelGGL(prep1, dim3(2048), dim3(256), 0, stream,
                     W_ih, W_hh, W_is0, b_is0, W_is1, b_is1, b_ih, b_hh,
                     whh_b, wmid_b, wc0, wc1, bc);
  hipLaunchKernelGGL(prep2, dim3(256), dim3(256), 0, stream, h0, h_hist, flags);
  hipLaunchKernelGGL(tembk, dim3(8192), dim3(256), 0, stream, x, temb);
  hipLaunchKernelGGL(gemmB, dim3(64, 16), dim3(256), 0, stream, temb, wmid_b, G);
  hipLaunchKernelGGL(lstmk, dim3(128), dim3(256), 0, stream,
                     x, c0, lens, whh_b, G, wc0, wc1, bc, h_hist, hfin, flags);
  hipLaunchKernelGGL(outk, dim3(64), dim3(256), 0, stream, hfin, W_o, b_o, out);
}